// Round 2
// 1503.623 us; speedup vs baseline: 1.0339x; 1.0339x over previous
//
#include <hip/hip_runtime.h>
#include <cstdint>
#include <cstddef>

typedef __attribute__((ext_vector_type(8))) short short8;
typedef __attribute__((ext_vector_type(4))) float f32x4;

#define DEV static __device__ __forceinline__

DEV short f2bf(float f) {
  unsigned u = __float_as_uint(f);
  u = (u + 0x7fffu + ((u >> 16) & 1u)) >> 16;
  return (short)u;
}

DEV void gload_lds16(const void* g, void* l) {
  __builtin_amdgcn_global_load_lds(
      (const __attribute__((address_space(1))) unsigned int*)(uintptr_t)g,
      (__attribute__((address_space(3))) unsigned int*)(uintptr_t)l,
      16, 0, 0);
}

// Swizzled staging source: chunk c (16B units) -> row = c>>2, slot = c&3,
// fetch global k-chunk (slot ^ (row&3)). LDS dest stays LINEAR (rule 21):
// LDS[row][slot] then holds k-chunk slot^(row&3); reader XORs the same way.
DEV size_t swz_src(int c, int K, int k0) {
  int r = c >> 2;
  return (size_t)r * K + k0 + (size_t)(((c ^ r) & 3) << 3);
}

// ---------------------------------------------------------------- transpose/convert
DEV void transpose_tile32(const float* __restrict__ src, int sld,
                          short* __restrict__ dst, int dld,
                          int sr, int sc, int tid)
{
  __shared__ float tile[32][33];
  const int r = tid >> 5, c = tid & 31;
#pragma unroll
  for (int i = 0; i < 4; ++i)
    tile[r + 8 * i][c] = src[(size_t)(sr + r + 8 * i) * sld + sc + c];
  __syncthreads();
#pragma unroll
  for (int i = 0; i < 4; ++i)
    dst[(size_t)(sc + r + 8 * i) * dld + sr + c] = f2bf(tile[c][r + 8 * i]);
}

__global__ __launch_bounds__(256) void convert_all_k(
    const float* __restrict__ wq, const float* __restrict__ wk,
    const float* __restrict__ wv, const float* __restrict__ wo,
    const float* __restrict__ w1, const float* __restrict__ w2,
    const float* __restrict__ wout,
    const float* __restrict__ bq, const float* __restrict__ bk,
    const float* __restrict__ bv,
    short* __restrict__ wqkv_bt, short* __restrict__ wo_bt,
    short* __restrict__ w1_bt, short* __restrict__ w2_bt,
    short* __restrict__ wout_bt, float* __restrict__ bqkv)
{
  const int t = blockIdx.x, tid = threadIdx.x;
  if (t < 3072) {                       // wq/wk/wv (512x512) -> wqkv_bt (1536x512)/layer
    int layer = t / 768, rem = t % 768, mat = rem / 256, tt = rem % 256;
    int tr = tt / 16, tc = tt % 16;
    const float* src = (mat == 0 ? wq : mat == 1 ? wk : wv) + (size_t)layer * 262144;
    short* dst = wqkv_bt + (size_t)layer * 786432 + (size_t)mat * 262144;
    transpose_tile32(src, 512, dst, 512, tr * 32, tc * 32, tid);
  } else if (t < 4096) {                // wo (512x512) -> (512x512)^T
    int t2 = t - 3072;
    int layer = t2 / 256, tt = t2 % 256, tr = tt / 16, tc = tt % 16;
    transpose_tile32(wo + (size_t)layer * 262144, 512,
                     wo_bt + (size_t)layer * 262144, 512, tr * 32, tc * 32, tid);
  } else if (t < 8192) {                // w1 (512x2048) -> (2048x512)
    int t2 = t - 4096;
    int layer = t2 / 1024, tt = t2 % 1024, tr = tt / 64, tc = tt % 64;
    transpose_tile32(w1 + (size_t)layer * 1048576, 2048,
                     w1_bt + (size_t)layer * 1048576, 512, tr * 32, tc * 32, tid);
  } else if (t < 12288) {               // w2 (2048x512) -> (512x2048)
    int t2 = t - 8192;
    int layer = t2 / 1024, tt = t2 % 1024, tr = tt / 16, tc = tt % 16;
    transpose_tile32(w2 + (size_t)layer * 1048576, 512,
                     w2_bt + (size_t)layer * 1048576, 2048, tr * 32, tc * 32, tid);
  } else if (t < 28288) {               // w_out (512x32000) -> (32000x512)
    int t2 = t - 12288;
    int tr = t2 / 1000, tc = t2 % 1000;
    transpose_tile32(wout, 32000, wout_bt, 512, tr * 32, tc * 32, tid);
  } else {                              // bias concat bq|bk|bv -> bqkv (4x1536)
    int idx = (t - 28288) * 256 + tid;
    int layer = idx / 1536, j = idx % 1536;
    float v = (j < 512) ? bq[layer * 512 + j]
            : (j < 1024) ? bk[layer * 512 + j - 512]
                         : bv[layer * 512 + j - 1024];
    bqkv[idx] = v;
  }
}

// ---------------------------------------------------------------- embedding + PE
__global__ __launch_bounds__(256) void embed_k(
    const int* __restrict__ tok, const float* __restrict__ emb, float* __restrict__ x)
{
  int idx = blockIdx.x * 256 + threadIdx.x;       // 4096*512 total
  int d = idx & 511, bs = idx >> 9, s = bs & 1023;
  int t = tok[bs];
  float dv = expf((float)(d & ~1) * (-9.210340371976184f / 512.f));
  float ang = (float)s * dv;
  float pe = (d & 1) ? cosf(ang) : sinf(ang);
  x[idx] = emb[(size_t)t * 512 + d] * 22.62741699796952f + pe;
}

// ---------------------------------------------------------------- layernorm -> bf16
__global__ __launch_bounds__(256) void layernorm_k(
    const float* __restrict__ x, const float* __restrict__ g,
    const float* __restrict__ b, short* __restrict__ out)
{
  const int row = blockIdx.x, tid = threadIdx.x;
  const float* xr = x + (size_t)row * 512;
  float v0 = xr[tid], v1 = xr[tid + 256];
  float s = v0 + v1;
  __shared__ float rs[4], rq[4];
#pragma unroll
  for (int o = 32; o > 0; o >>= 1) s += __shfl_down(s, o, 64);
  if ((tid & 63) == 0) rs[tid >> 6] = s;
  __syncthreads();
  float mean = (rs[0] + rs[1] + rs[2] + rs[3]) * (1.f / 512.f);
  float d0 = v0 - mean, d1 = v1 - mean;
  float q = d0 * d0 + d1 * d1;
#pragma unroll
  for (int o = 32; o > 0; o >>= 1) q += __shfl_down(q, o, 64);
  if ((tid & 63) == 0) rq[tid >> 6] = q;
  __syncthreads();
  float var = (rq[0] + rq[1] + rq[2] + rq[3]) * (1.f / 512.f);
  float inv = 1.f / (sqrtf(var) + 1e-6f);
  out[(size_t)row * 512 + tid]       = f2bf(g[tid] * d0 * inv + b[tid]);
  out[(size_t)row * 512 + tid + 256] = f2bf(g[tid + 256] * d1 * inv + b[tid + 256]);
}

// ---------------------------------------------------------------- GEMM: C = A(bf16,MxK) @ Bt^T + bias [+gelu][+resid]
// 128x128 tile, 4 waves (2x2), BK=32; XOR slot swizzle on LDS reads
// (source pre-swizzled, linear global_load_lds dest per guide rule 21).
template<bool GELU, bool RES, bool OUTBF16>
__global__ __launch_bounds__(256) void gemm_bt(
    const short* __restrict__ A, const short* __restrict__ Bt,
    const float* __restrict__ bias, const float* __restrict__ resid,
    void* __restrict__ out, int M, int N, int K)
{
  __shared__ __align__(16) short lA[128 * 32];
  __shared__ __align__(16) short lB[128 * 32];
  const int tid = threadIdx.x;
  const int lane = tid & 63;
  const int w = tid >> 6, wr = w >> 1, wc = w & 1;
  const int lr = lane & 15, quad = lane >> 4;
  const int m0 = blockIdx.y * 128, n0 = blockIdx.x * 128;

  f32x4 acc[4][4] = {};

  const int c1 = tid, c2 = tid + 256;
  const short* Ab = A + (size_t)m0 * K;
  const short* Bb = Bt + (size_t)n0 * K;
  const int sl = ((quad ^ lr) & 3) << 3;   // swizzled 8-short slot offset

  for (int k0 = 0; k0 < K; k0 += 32) {
    gload_lds16(Ab + swz_src(c1, K, k0), lA + c1 * 8);
    gload_lds16(Ab + swz_src(c2, K, k0), lA + c2 * 8);
    gload_lds16(Bb + swz_src(c1, K, k0), lB + c1 * 8);
    gload_lds16(Bb + swz_src(c2, K, k0), lB + c2 * 8);
    __syncthreads();
    short8 af[4], bf[4];
#pragma unroll
    for (int mi = 0; mi < 4; ++mi)
      af[mi] = *(const short8*)&lA[(wr * 64 + mi * 16 + lr) * 32 + sl];
#pragma unroll
    for (int ni = 0; ni < 4; ++ni)
      bf[ni] = *(const short8*)&lB[(wc * 64 + ni * 16 + lr) * 32 + sl];
#pragma unroll
    for (int mi = 0; mi < 4; ++mi)
#pragma unroll
      for (int ni = 0; ni < 4; ++ni)
        acc[mi][ni] = __builtin_amdgcn_mfma_f32_16x16x32_bf16(af[mi], bf[ni], acc[mi][ni], 0, 0, 0);
    __syncthreads();
  }

#pragma unroll
  for (int mi = 0; mi < 4; ++mi) {
#pragma unroll
    for (int ni = 0; ni < 4; ++ni) {
      const int n = n0 + wc * 64 + ni * 16 + lr;
      const float bn = bias[n];
#pragma unroll
      for (int r = 0; r < 4; ++r) {
        const int m = m0 + wr * 64 + mi * 16 + quad * 4 + r;
        float v = acc[mi][ni][r] + bn;
        if (GELU) v = 0.5f * v * (1.f + erff(v * 0.7071067811865475f));
        if (RES) v += resid[(size_t)m * N + n];
        if (OUTBF16) ((short*)out)[(size_t)m * N + n] = f2bf(v);
        else         ((float*)out)[(size_t)m * N + n] = v;
      }
    }
  }
}

// ---------------------------------------------------------------- GEMM 64x128 tile
// For N=512 GEMMs (WO, FFN2): BM=64 doubles the grid (128 -> 256 blocks) so all
// 256 CUs get work. 4 waves arranged 1x4 in N; per-wave 64x32 output (acc[4][2]).
// Same K-order as gemm_bt -> bitwise-identical accumulation.
template<bool GELU, bool RES, bool OUTBF16>
__global__ __launch_bounds__(256) void gemm64_bt(
    const short* __restrict__ A, const short* __restrict__ Bt,
    const float* __restrict__ bias, const float* __restrict__ resid,
    void* __restrict__ out, int M, int N, int K)
{
  __shared__ __align__(16) short lA[64 * 32];
  __shared__ __align__(16) short lB[128 * 32];
  const int tid = threadIdx.x;
  const int lane = tid & 63;
  const int w = tid >> 6;               // N-strip 0..3
  const int lr = lane & 15, quad = lane >> 4;
  const int m0 = blockIdx.y * 64, n0 = blockIdx.x * 128;

  f32x4 acc[4][2] = {};

  const int c2 = tid + 256;
  const short* Ab = A + (size_t)m0 * K;
  const short* Bb = Bt + (size_t)n0 * K;
  const int sl = ((quad ^ lr) & 3) << 3;

  for (int k0 = 0; k0 < K; k0 += 32) {
    gload_lds16(Ab + swz_src(tid, K, k0), lA + tid * 8);   // 256 chunks = full A tile
    gload_lds16(Bb + swz_src(tid, K, k0), lB + tid * 8);
    gload_lds16(Bb + swz_src(c2,  K, k0), lB + c2 * 8);
    __syncthreads();
    short8 af[4], bf[2];
#pragma unroll
    for (int mi = 0; mi < 4; ++mi)
      af[mi] = *(const short8*)&lA[(mi * 16 + lr) * 32 + sl];
#pragma unroll
    for (int ni = 0; ni < 2; ++ni)
      bf[ni] = *(const short8*)&lB[(w * 32 + ni * 16 + lr) * 32 + sl];
#pragma unroll
    for (int mi = 0; mi < 4; ++mi)
#pragma unroll
      for (int ni = 0; ni < 2; ++ni)
        acc[mi][ni] = __builtin_amdgcn_mfma_f32_16x16x32_bf16(af[mi], bf[ni], acc[mi][ni], 0, 0, 0);
    __syncthreads();
  }

#pragma unroll
  for (int mi = 0; mi < 4; ++mi) {
#pragma unroll
    for (int ni = 0; ni < 2; ++ni) {
      const int n = n0 + w * 32 + ni * 16 + lr;
      const float bn = bias[n];
#pragma unroll
      for (int r = 0; r < 4; ++r) {
        const int m = m0 + mi * 16 + quad * 4 + r;
        float v = acc[mi][ni][r] + bn;
        if (GELU) v = 0.5f * v * (1.f + erff(v * 0.7071067811865475f));
        if (RES) v += resid[(size_t)m * N + n];
        if (OUTBF16) ((short*)out)[(size_t)m * N + n] = f2bf(v);
        else         ((float*)out)[(size_t)m * N + n] = v;
      }
    }
  }
}

// ---------------------------------------------------------------- flash attention
// qkv: (B*S, 1536) bf16, q|k|v sections of 512 (= 8 heads x 64)
// out: (B*S, 512) bf16
__global__ __launch_bounds__(256) void attn_k(
    const short* __restrict__ qkv, short* __restrict__ attn_out)
{
  const int bh = blockIdx.y, b = bh >> 3, h = bh & 7;
  const int q0 = blockIdx.x * 64;
  const int tid = threadIdx.x, lane = tid & 63, w = tid >> 6;
  const int lr = lane & 15, quad = lane >> 4;
  const int RS = 1536;

  const short* qb = qkv + (size_t)b * 1024 * RS + h * 64;
  const short* kb = qb + 512;
  const short* vb = qb + 1024;

  __shared__ __align__(16) short lK[32 * 64];
  __shared__ __align__(16) short lVt[64 * 32];
  __shared__ __align__(16) short lP[4][16 * 32];

  const int qrow = q0 + w * 16 + lr;
  const short8 aq0 = *(const short8*)(qb + (size_t)qrow * RS + quad * 8);
  const short8 aq1 = *(const short8*)(qb + (size_t)qrow * RS + 32 + quad * 8);

  f32x4 o[4] = {};
  float mrow[4] = {-1e30f, -1e30f, -1e30f, -1e30f};
  float lrow[4] = {0.f, 0.f, 0.f, 0.f};

  const int kend = q0 + 64;
  for (int kt = 0; kt < kend; kt += 32) {
    {
      int r = tid >> 3, c = (tid & 7) * 8;
      gload_lds16(kb + (size_t)(kt + r) * RS + c, lK + r * 64 + c);
      short8 vv = *(const short8*)(vb + (size_t)(kt + r) * RS + c);
#pragma unroll
      for (int j = 0; j < 8; ++j) lVt[(c + j) * 32 + r] = vv[j];
    }
    __syncthreads();

    f32x4 st[2];
#pragma unroll
    for (int t = 0; t < 2; ++t) {
      const short8 bk0 = *(const short8*)&lK[(t * 16 + lr) * 64 + quad * 8];
      const short8 bk1 = *(const short8*)&lK[(t * 16 + lr) * 64 + 32 + quad * 8];
      f32x4 z = {0.f, 0.f, 0.f, 0.f};
      z = __builtin_amdgcn_mfma_f32_16x16x32_bf16(aq0, bk0, z, 0, 0, 0);
      z = __builtin_amdgcn_mfma_f32_16x16x32_bf16(aq1, bk1, z, 0, 0, 0);
      st[t] = z;
    }
    float sc[2][4];
#pragma unroll
    for (int t = 0; t < 2; ++t)
#pragma unroll
      for (int r = 0; r < 4; ++r) {
        int qg = q0 + w * 16 + quad * 4 + r;
        int kg = kt + t * 16 + lr;
        sc[t][r] = (kg <= qg) ? st[t][r] * 0.125f : -1e30f;
      }
#pragma unroll
    for (int r = 0; r < 4; ++r) {
      float tm = fmaxf(sc[0][r], sc[1][r]);
#pragma unroll
      for (int off = 1; off < 16; off <<= 1) tm = fmaxf(tm, __shfl_xor(tm, off, 64));
      float mnew = fmaxf(mrow[r], tm);
      float alpha = __expf(mrow[r] - mnew);
      mrow[r] = mnew;
      float p0 = __expf(sc[0][r] - mnew);
      float p1 = __expf(sc[1][r] - mnew);
      lP[w][(quad * 4 + r) * 32 + lr]      = f2bf(p0);
      lP[w][(quad * 4 + r) * 32 + 16 + lr] = f2bf(p1);
      float ps = p0 + p1;
#pragma unroll
      for (int off = 1; off < 16; off <<= 1) ps += __shfl_xor(ps, off, 64);
      lrow[r] = lrow[r] * alpha + ps;
#pragma unroll
      for (int ni = 0; ni < 4; ++ni) o[ni][r] *= alpha;
    }
    const short8 pa = *(const short8*)&lP[w][lr * 32 + quad * 8];
#pragma unroll
    for (int ni = 0; ni < 4; ++ni) {
      const short8 bv = *(const short8*)&lVt[(ni * 16 + lr) * 32 + quad * 8];
      o[ni] = __builtin_amdgcn_mfma_f32_16x16x32_bf16(pa, bv, o[ni], 0, 0, 0);
    }
    __syncthreads();
  }

#pragma unroll
  for (int ni = 0; ni < 4; ++ni)
#pragma unroll
    for (int r = 0; r < 4; ++r) {
      int qg = q0 + w * 16 + quad * 4 + r;
      float val = o[ni][r] / lrow[r];
      attn_out[((size_t)(b * 1024 + qg)) * 512 + h * 64 + ni * 16 + lr] = f2bf(val);
    }
}

// ---------------------------------------------------------------- launch
extern "C" void kernel_launch(void* const* d_in, const int* in_sizes, int n_in,
                              void* d_out, int out_size, void* d_ws, size_t ws_size,
                              hipStream_t stream)
{
  (void)in_sizes; (void)n_in; (void)out_size; (void)ws_size;
  const int*   tokens  = (const int*)d_in[0];
  const float* tok_emb = (const float*)d_in[1];
  const float* gamma1  = (const float*)d_in[2];
  const float* beta1   = (const float*)d_in[3];
  const float* wq = (const float*)d_in[4];
  const float* bq = (const float*)d_in[5];
  const float* wk = (const float*)d_in[6];
  const float* bk = (const float*)d_in[7];
  const float* wv = (const float*)d_in[8];
  const float* bv = (const float*)d_in[9];
  const float* wo = (const float*)d_in[10];
  const float* bo = (const float*)d_in[11];
  const float* gamma2 = (const float*)d_in[12];
  const float* beta2  = (const float*)d_in[13];
  const float* w1 = (const float*)d_in[14];
  const float* b1 = (const float*)d_in[15];
  const float* w2 = (const float*)d_in[16];
  const float* b2 = (const float*)d_in[17];
  const float* gamma_f = (const float*)d_in[18];
  const float* beta_f  = (const float*)d_in[19];
  const float* w_out   = (const float*)d_in[20];
  const float* b_out   = (const float*)d_in[21];

  char* ws = (char*)d_ws;
  size_t off = 0;
  auto alloc = [&](size_t bytes) -> void* {
    void* p = ws + off; off += (bytes + 255) & ~(size_t)255; return p;
  };
  short* wqkv_bt = (short*)alloc(4ull * 1536 * 512 * 2);
  short* wo_bt   = (short*)alloc(4ull * 512 * 512 * 2);
  short* w1_bt   = (short*)alloc(4ull * 2048 * 512 * 2);
  short* w2_bt   = (short*)alloc(4ull * 512 * 2048 * 2);
  short* wout_bt = (short*)alloc(32000ull * 512 * 2);
  float* bqkv    = (float*)alloc(4ull * 1536 * 4);
  float* x       = (float*)alloc(4096ull * 512 * 4);
  short* hbuf    = (short*)alloc(4096ull * 512 * 2);
  short* qkv     = (short*)alloc(4096ull * 1536 * 2);
  short* attnout = (short*)alloc(4096ull * 512 * 2);
  short* ffn1    = (short*)alloc(4096ull * 2048 * 2);
  short* xf      = (short*)alloc(4096ull * 512 * 2);

  convert_all_k<<<28312, 256, 0, stream>>>(wq, wk, wv, wo, w1, w2, w_out, bq, bk, bv,
                                           wqkv_bt, wo_bt, w1_bt, w2_bt, wout_bt, bqkv);
  embed_k<<<8192, 256, 0, stream>>>(tokens, tok_emb, x);
  for (int l = 0; l < 4; ++l) {
    layernorm_k<<<4096, 256, 0, stream>>>(x, gamma1 + l * 512, beta1 + l * 512, hbuf);
    gemm_bt<false, false, true><<<dim3(12, 32), 256, 0, stream>>>(
        hbuf, wqkv_bt + (size_t)l * 786432, bqkv + l * 1536, nullptr, qkv, 4096, 1536, 512);
    attn_k<<<dim3(16, 32), 256, 0, stream>>>(qkv, attnout);
    gemm64_bt<false, true, false><<<dim3(4, 64), 256, 0, stream>>>(
        attnout, wo_bt + (size_t)l * 262144, bo + l * 512, x, x, 4096, 512, 512);
    layernorm_k<<<4096, 256, 0, stream>>>(x, gamma2 + l * 512, beta2 + l * 512, hbuf);
    gemm_bt<true, false, true><<<dim3(16, 32), 256, 0, stream>>>(
        hbuf, w1_bt + (size_t)l * 1048576, b1 + l * 2048, nullptr, ffn1, 4096, 2048, 512);
    gemm64_bt<false, true, false><<<dim3(4, 64), 256, 0, stream>>>(
        ffn1, w2_bt + (size_t)l * 1048576, b2 + l * 512, x, x, 4096, 512, 2048);
  }
  layernorm_k<<<4096, 256, 0, stream>>>(x, gamma_f, beta_f, xf);
  gemm_bt<false, false, false><<<dim3(250, 32), 256, 0, stream>>>(
      xf, wout_bt, b_out, nullptr, d_out, 4096, 32000, 512);
}

// Round 3
// 1455.039 us; speedup vs baseline: 1.0685x; 1.0334x over previous
//
#include <hip/hip_runtime.h>
#include <cstdint>
#include <cstddef>

typedef __attribute__((ext_vector_type(8))) short short8;
typedef __attribute__((ext_vector_type(4))) float f32x4;

#define DEV static __device__ __forceinline__

DEV short f2bf(float f) {
  unsigned u = __float_as_uint(f);
  u = (u + 0x7fffu + ((u >> 16) & 1u)) >> 16;
  return (short)u;
}

DEV void gload_lds16(const void* g, void* l) {
  __builtin_amdgcn_global_load_lds(
      (const __attribute__((address_space(1))) unsigned int*)(uintptr_t)g,
      (__attribute__((address_space(3))) unsigned int*)(uintptr_t)l,
      16, 0, 0);
}

// Swizzled staging source: chunk c (16B units) -> row = c>>2, slot = c&3,
// fetch global k-chunk (slot ^ (row&3)). LDS dest stays LINEAR (rule 21):
// LDS[row][slot] then holds k-chunk slot^(row&3); reader XORs the same way.
DEV size_t swz_src(int c, int K) {
  int r = c >> 2;
  return (size_t)r * K + (size_t)(((c ^ r) & 3) << 3);
}

// ---------------------------------------------------------------- transpose/convert
DEV void transpose_tile32(const float* __restrict__ src, int sld,
                          short* __restrict__ dst, int dld,
                          int sr, int sc, int tid)
{
  __shared__ float tile[32][33];
  const int r = tid >> 5, c = tid & 31;
#pragma unroll
  for (int i = 0; i < 4; ++i)
    tile[r + 8 * i][c] = src[(size_t)(sr + r + 8 * i) * sld + sc + c];
  __syncthreads();
#pragma unroll
  for (int i = 0; i < 4; ++i)
    dst[(size_t)(sc + r + 8 * i) * dld + sr + c] = f2bf(tile[c][r + 8 * i]);
}

__global__ __launch_bounds__(256) void convert_all_k(
    const float* __restrict__ wq, const float* __restrict__ wk,
    const float* __restrict__ wv, const float* __restrict__ wo,
    const float* __restrict__ w1, const float* __restrict__ w2,
    const float* __restrict__ wout,
    const float* __restrict__ bq, const float* __restrict__ bk,
    const float* __restrict__ bv,
    short* __restrict__ wqkv_bt, short* __restrict__ wo_bt,
    short* __restrict__ w1_bt, short* __restrict__ w2_bt,
    short* __restrict__ wout_bt, float* __restrict__ bqkv)
{
  const int t = blockIdx.x, tid = threadIdx.x;
  if (t < 3072) {                       // wq/wk/wv (512x512) -> wqkv_bt (1536x512)/layer
    int layer = t / 768, rem = t % 768, mat = rem / 256, tt = rem % 256;
    int tr = tt / 16, tc = tt % 16;
    const float* src = (mat == 0 ? wq : mat == 1 ? wk : wv) + (size_t)layer * 262144;
    short* dst = wqkv_bt + (size_t)layer * 786432 + (size_t)mat * 262144;
    transpose_tile32(src, 512, dst, 512, tr * 32, tc * 32, tid);
  } else if (t < 4096) {                // wo (512x512) -> (512x512)^T
    int t2 = t - 3072;
    int layer = t2 / 256, tt = t2 % 256, tr = tt / 16, tc = tt % 16;
    transpose_tile32(wo + (size_t)layer * 262144, 512,
                     wo_bt + (size_t)layer * 262144, 512, tr * 32, tc * 32, tid);
  } else if (t < 8192) {                // w1 (512x2048) -> (2048x512)
    int t2 = t - 4096;
    int layer = t2 / 1024, tt = t2 % 1024, tr = tt / 64, tc = tt % 64;
    transpose_tile32(w1 + (size_t)layer * 1048576, 2048,
                     w1_bt + (size_t)layer * 1048576, 512, tr * 32, tc * 32, tid);
  } else if (t < 12288) {               // w2 (2048x512) -> (512x2048)
    int t2 = t - 8192;
    int layer = t2 / 1024, tt = t2 % 1024, tr = tt / 16, tc = tt % 16;
    transpose_tile32(w2 + (size_t)layer * 1048576, 512,
                     w2_bt + (size_t)layer * 1048576, 2048, tr * 32, tc * 32, tid);
  } else if (t < 28288) {               // w_out (512x32000) -> (32000x512)
    int t2 = t - 12288;
    int tr = t2 / 1000, tc = t2 % 1000;
    transpose_tile32(wout, 32000, wout_bt, 512, tr * 32, tc * 32, tid);
  } else {                              // bias concat bq|bk|bv -> bqkv (4x1536)
    int idx = (t - 28288) * 256 + tid;
    int layer = idx / 1536, j = idx % 1536;
    float v = (j < 512) ? bq[layer * 512 + j]
            : (j < 1024) ? bk[layer * 512 + j - 512]
                         : bv[layer * 512 + j - 1024];
    bqkv[idx] = v;
  }
}

// ---------------------------------------------------------------- embedding + PE
__global__ __launch_bounds__(256) void embed_k(
    const int* __restrict__ tok, const float* __restrict__ emb, float* __restrict__ x)
{
  int idx = blockIdx.x * 256 + threadIdx.x;       // 4096*512 total
  int d = idx & 511, bs = idx >> 9, s = bs & 1023;
  int t = tok[bs];
  float dv = expf((float)(d & ~1) * (-9.210340371976184f / 512.f));
  float ang = (float)s * dv;
  float pe = (d & 1) ? cosf(ang) : sinf(ang);
  x[idx] = emb[(size_t)t * 512 + d] * 22.62741699796952f + pe;
}

// ---------------------------------------------------------------- layernorm -> bf16
__global__ __launch_bounds__(256) void layernorm_k(
    const float* __restrict__ x, const float* __restrict__ g,
    const float* __restrict__ b, short* __restrict__ out)
{
  const int row = blockIdx.x, tid = threadIdx.x;
  const float* xr = x + (size_t)row * 512;
  float v0 = xr[tid], v1 = xr[tid + 256];
  float s = v0 + v1;
  __shared__ float rs[4], rq[4];
#pragma unroll
  for (int o = 32; o > 0; o >>= 1) s += __shfl_down(s, o, 64);
  if ((tid & 63) == 0) rs[tid >> 6] = s;
  __syncthreads();
  float mean = (rs[0] + rs[1] + rs[2] + rs[3]) * (1.f / 512.f);
  float d0 = v0 - mean, d1 = v1 - mean;
  float q = d0 * d0 + d1 * d1;
#pragma unroll
  for (int o = 32; o > 0; o >>= 1) q += __shfl_down(q, o, 64);
  if ((tid & 63) == 0) rq[tid >> 6] = q;
  __syncthreads();
  float var = (rq[0] + rq[1] + rq[2] + rq[3]) * (1.f / 512.f);
  float inv = 1.f / (sqrtf(var) + 1e-6f);
  out[(size_t)row * 512 + tid]       = f2bf(g[tid] * d0 * inv + b[tid]);
  out[(size_t)row * 512 + tid + 256] = f2bf(g[tid + 256] * d1 * inv + b[tid + 256]);
}

// ---------------------------------------------------------------- GEMM: C = A(bf16,MxK) @ Bt^T + bias [+gelu][+resid]
// 128x128 tile, 4 waves (2x2), BK=32. 2-phase double-buffered (T3 minimum
// recipe): issue next K-step's global_load_lds BEFORE reading current buffer;
// ONE __syncthreads per step (its vmcnt(0)+lgkmcnt(0) drain waits on loads
// that have been in flight across the whole compute phase).
template<bool GELU, bool RES, bool OUTBF16>
__global__ __launch_bounds__(256) void gemm_bt(
    const short* __restrict__ A, const short* __restrict__ Bt,
    const float* __restrict__ bias, const float* __restrict__ resid,
    void* __restrict__ out, int M, int N, int K)
{
  __shared__ __align__(16) short lA[2][128 * 32];
  __shared__ __align__(16) short lB[2][128 * 32];
  const int tid = threadIdx.x;
  const int lane = tid & 63;
  const int w = tid >> 6, wr = w >> 1, wc = w & 1;
  const int lr = lane & 15, quad = lane >> 4;
  const int m0 = blockIdx.y * 128, n0 = blockIdx.x * 128;

  f32x4 acc[4][4] = {};

  const int c1 = tid, c2 = tid + 256;
  const short* Ab = A + (size_t)m0 * K;
  const short* Bb = Bt + (size_t)n0 * K;
  const size_t oa1 = swz_src(c1, K), oa2 = swz_src(c2, K);
  const int sl = ((quad ^ lr) & 3) << 3;   // swizzled 8-short slot offset

  // prologue: stage k0=0 into buf 0
  gload_lds16(Ab + oa1, lA[0] + c1 * 8);
  gload_lds16(Ab + oa2, lA[0] + c2 * 8);
  gload_lds16(Bb + oa1, lB[0] + c1 * 8);
  gload_lds16(Bb + oa2, lB[0] + c2 * 8);
  __syncthreads();

  int cur = 0;
  for (int k0 = 0; k0 < K; k0 += 32) {
    if (k0 + 32 < K) {                      // prefetch next step into other buf
      gload_lds16(Ab + oa1 + k0 + 32, lA[cur ^ 1] + c1 * 8);
      gload_lds16(Ab + oa2 + k0 + 32, lA[cur ^ 1] + c2 * 8);
      gload_lds16(Bb + oa1 + k0 + 32, lB[cur ^ 1] + c1 * 8);
      gload_lds16(Bb + oa2 + k0 + 32, lB[cur ^ 1] + c2 * 8);
    }
    short8 af[4], bf[4];
#pragma unroll
    for (int mi = 0; mi < 4; ++mi)
      af[mi] = *(const short8*)&lA[cur][(wr * 64 + mi * 16 + lr) * 32 + sl];
#pragma unroll
    for (int ni = 0; ni < 4; ++ni)
      bf[ni] = *(const short8*)&lB[cur][(wc * 64 + ni * 16 + lr) * 32 + sl];
#pragma unroll
    for (int mi = 0; mi < 4; ++mi)
#pragma unroll
      for (int ni = 0; ni < 4; ++ni)
        acc[mi][ni] = __builtin_amdgcn_mfma_f32_16x16x32_bf16(af[mi], bf[ni], acc[mi][ni], 0, 0, 0);
    __syncthreads();
    cur ^= 1;
  }

#pragma unroll
  for (int mi = 0; mi < 4; ++mi) {
#pragma unroll
    for (int ni = 0; ni < 4; ++ni) {
      const int n = n0 + wc * 64 + ni * 16 + lr;
      const float bn = bias[n];
#pragma unroll
      for (int r = 0; r < 4; ++r) {
        const int m = m0 + wr * 64 + mi * 16 + quad * 4 + r;
        float v = acc[mi][ni][r] + bn;
        if (GELU) v = 0.5f * v * (1.f + erff(v * 0.7071067811865475f));
        if (RES) v += resid[(size_t)m * N + n];
        if (OUTBF16) ((short*)out)[(size_t)m * N + n] = f2bf(v);
        else         ((float*)out)[(size_t)m * N + n] = v;
      }
    }
  }
}

// ---------------------------------------------------------------- GEMM 64x128 tile, 2-phase dbuf
// For N-small GEMMs (QKV N=1536, WO/FFN2 N=512): BM=64 doubles/triples grid
// so all 256 CUs stay busy; dbuf hides load latency at 1-3 blocks/CU.
template<bool GELU, bool RES, bool OUTBF16>
__global__ __launch_bounds__(256) void gemm64_bt(
    const short* __restrict__ A, const short* __restrict__ Bt,
    const float* __restrict__ bias, const float* __restrict__ resid,
    void* __restrict__ out, int M, int N, int K)
{
  __shared__ __align__(16) short lA[2][64 * 32];
  __shared__ __align__(16) short lB[2][128 * 32];
  const int tid = threadIdx.x;
  const int lane = tid & 63;
  const int w = tid >> 6;               // N-strip 0..3
  const int lr = lane & 15, quad = lane >> 4;
  const int m0 = blockIdx.y * 64, n0 = blockIdx.x * 128;

  f32x4 acc[4][2] = {};

  const int c2 = tid + 256;
  const short* Ab = A + (size_t)m0 * K;
  const short* Bb = Bt + (size_t)n0 * K;
  const size_t oa1 = swz_src(tid, K), oa2 = swz_src(c2, K);
  const int sl = ((quad ^ lr) & 3) << 3;

  gload_lds16(Ab + oa1, lA[0] + tid * 8);
  gload_lds16(Bb + oa1, lB[0] + tid * 8);
  gload_lds16(Bb + oa2, lB[0] + c2 * 8);
  __syncthreads();

  int cur = 0;
  for (int k0 = 0; k0 < K; k0 += 32) {
    if (k0 + 32 < K) {
      gload_lds16(Ab + oa1 + k0 + 32, lA[cur ^ 1] + tid * 8);
      gload_lds16(Bb + oa1 + k0 + 32, lB[cur ^ 1] + tid * 8);
      gload_lds16(Bb + oa2 + k0 + 32, lB[cur ^ 1] + c2 * 8);
    }
    short8 af[4], bf[2];
#pragma unroll
    for (int mi = 0; mi < 4; ++mi)
      af[mi] = *(const short8*)&lA[cur][(mi * 16 + lr) * 32 + sl];
#pragma unroll
    for (int ni = 0; ni < 2; ++ni)
      bf[ni] = *(const short8*)&lB[cur][(w * 32 + ni * 16 + lr) * 32 + sl];
#pragma unroll
    for (int mi = 0; mi < 4; ++mi)
#pragma unroll
      for (int ni = 0; ni < 2; ++ni)
        acc[mi][ni] = __builtin_amdgcn_mfma_f32_16x16x32_bf16(af[mi], bf[ni], acc[mi][ni], 0, 0, 0);
    __syncthreads();
    cur ^= 1;
  }

#pragma unroll
  for (int mi = 0; mi < 4; ++mi) {
#pragma unroll
    for (int ni = 0; ni < 2; ++ni) {
      const int n = n0 + w * 32 + ni * 16 + lr;
      const float bn = bias[n];
#pragma unroll
      for (int r = 0; r < 4; ++r) {
        const int m = m0 + mi * 16 + quad * 4 + r;
        float v = acc[mi][ni][r] + bn;
        if (GELU) v = 0.5f * v * (1.f + erff(v * 0.7071067811865475f));
        if (RES) v += resid[(size_t)m * N + n];
        if (OUTBF16) ((short*)out)[(size_t)m * N + n] = f2bf(v);
        else         ((float*)out)[(size_t)m * N + n] = v;
      }
    }
  }
}

// ---------------------------------------------------------------- flash attention
// qkv: (B*S, 1536) bf16, q|k|v sections of 512 (= 8 heads x 64)
// out: (B*S, 512) bf16
__global__ __launch_bounds__(256) void attn_k(
    const short* __restrict__ qkv, short* __restrict__ attn_out)
{
  const int bh = blockIdx.y, b = bh >> 3, h = bh & 7;
  const int q0 = blockIdx.x * 64;
  const int tid = threadIdx.x, lane = tid & 63, w = tid >> 6;
  const int lr = lane & 15, quad = lane >> 4;
  const int RS = 1536;

  const short* qb = qkv + (size_t)b * 1024 * RS + h * 64;
  const short* kb = qb + 512;
  const short* vb = qb + 1024;

  __shared__ __align__(16) short lK[32 * 64];
  __shared__ __align__(16) short lVt[64 * 32];
  __shared__ __align__(16) short lP[4][16 * 32];

  const int qrow = q0 + w * 16 + lr;
  const short8 aq0 = *(const short8*)(qb + (size_t)qrow * RS + quad * 8);
  const short8 aq1 = *(const short8*)(qb + (size_t)qrow * RS + 32 + quad * 8);

  f32x4 o[4] = {};
  float mrow[4] = {-1e30f, -1e30f, -1e30f, -1e30f};
  float lrow[4] = {0.f, 0.f, 0.f, 0.f};

  const int kend = q0 + 64;
  for (int kt = 0; kt < kend; kt += 32) {
    {
      int r = tid >> 3, c = (tid & 7) * 8;
      gload_lds16(kb + (size_t)(kt + r) * RS + c, lK + r * 64 + c);
      short8 vv = *(const short8*)(vb + (size_t)(kt + r) * RS + c);
#pragma unroll
      for (int j = 0; j < 8; ++j) lVt[(c + j) * 32 + r] = vv[j];
    }
    __syncthreads();

    f32x4 st[2];
#pragma unroll
    for (int t = 0; t < 2; ++t) {
      const short8 bk0 = *(const short8*)&lK[(t * 16 + lr) * 64 + quad * 8];
      const short8 bk1 = *(const short8*)&lK[(t * 16 + lr) * 64 + 32 + quad * 8];
      f32x4 z = {0.f, 0.f, 0.f, 0.f};
      z = __builtin_amdgcn_mfma_f32_16x16x32_bf16(aq0, bk0, z, 0, 0, 0);
      z = __builtin_amdgcn_mfma_f32_16x16x32_bf16(aq1, bk1, z, 0, 0, 0);
      st[t] = z;
    }
    float sc[2][4];
#pragma unroll
    for (int t = 0; t < 2; ++t)
#pragma unroll
      for (int r = 0; r < 4; ++r) {
        int qg = q0 + w * 16 + quad * 4 + r;
        int kg = kt + t * 16 + lr;
        sc[t][r] = (kg <= qg) ? st[t][r] * 0.125f : -1e30f;
      }
#pragma unroll
    for (int r = 0; r < 4; ++r) {
      float tm = fmaxf(sc[0][r], sc[1][r]);
#pragma unroll
      for (int off = 1; off < 16; off <<= 1) tm = fmaxf(tm, __shfl_xor(tm, off, 64));
      float mnew = fmaxf(mrow[r], tm);
      float alpha = __expf(mrow[r] - mnew);
      mrow[r] = mnew;
      float p0 = __expf(sc[0][r] - mnew);
      float p1 = __expf(sc[1][r] - mnew);
      lP[w][(quad * 4 + r) * 32 + lr]      = f2bf(p0);
      lP[w][(quad * 4 + r) * 32 + 16 + lr] = f2bf(p1);
      float ps = p0 + p1;
#pragma unroll
      for (int off = 1; off < 16; off <<= 1) ps += __shfl_xor(ps, off, 64);
      lrow[r] = lrow[r] * alpha + ps;
#pragma unroll
      for (int ni = 0; ni < 4; ++ni) o[ni][r] *= alpha;
    }
    const short8 pa = *(const short8*)&lP[w][lr * 32 + quad * 8];
#pragma unroll
    for (int ni = 0; ni < 4; ++ni) {
      const short8 bv = *(const short8*)&lVt[(ni * 16 + lr) * 32 + quad * 8];
      o[ni] = __builtin_amdgcn_mfma_f32_16x16x32_bf16(pa, bv, o[ni], 0, 0, 0);
    }
    __syncthreads();
  }

#pragma unroll
  for (int ni = 0; ni < 4; ++ni)
#pragma unroll
    for (int r = 0; r < 4; ++r) {
      int qg = q0 + w * 16 + quad * 4 + r;
      float val = o[ni][r] / lrow[r];
      attn_out[((size_t)(b * 1024 + qg)) * 512 + h * 64 + ni * 16 + lr] = f2bf(val);
    }
}

// ---------------------------------------------------------------- launch
extern "C" void kernel_launch(void* const* d_in, const int* in_sizes, int n_in,
                              void* d_out, int out_size, void* d_ws, size_t ws_size,
                              hipStream_t stream)
{
  (void)in_sizes; (void)n_in; (void)out_size; (void)ws_size;
  const int*   tokens  = (const int*)d_in[0];
  const float* tok_emb = (const float*)d_in[1];
  const float* gamma1  = (const float*)d_in[2];
  const float* beta1   = (const float*)d_in[3];
  const float* wq = (const float*)d_in[4];
  const float* bq = (const float*)d_in[5];
  const float* wk = (const float*)d_in[6];
  const float* bk = (const float*)d_in[7];
  const float* wv = (const float*)d_in[8];
  const float* bv = (const float*)d_in[9];
  const float* wo = (const float*)d_in[10];
  const float* bo = (const float*)d_in[11];
  const float* gamma2 = (const float*)d_in[12];
  const float* beta2  = (const float*)d_in[13];
  const float* w1 = (const float*)d_in[14];
  const float* b1 = (const float*)d_in[15];
  const float* w2 = (const float*)d_in[16];
  const float* b2 = (const float*)d_in[17];
  const float* gamma_f = (const float*)d_in[18];
  const float* beta_f  = (const float*)d_in[19];
  const float* w_out   = (const float*)d_in[20];
  const float* b_out   = (const float*)d_in[21];

  char* ws = (char*)d_ws;
  size_t off = 0;
  auto alloc = [&](size_t bytes) -> void* {
    void* p = ws + off; off += (bytes + 255) & ~(size_t)255; return p;
  };
  short* wqkv_bt = (short*)alloc(4ull * 1536 * 512 * 2);
  short* wo_bt   = (short*)alloc(4ull * 512 * 512 * 2);
  short* w1_bt   = (short*)alloc(4ull * 2048 * 512 * 2);
  short* w2_bt   = (short*)alloc(4ull * 512 * 2048 * 2);
  short* wout_bt = (short*)alloc(32000ull * 512 * 2);
  float* bqkv    = (float*)alloc(4ull * 1536 * 4);
  float* x       = (float*)alloc(4096ull * 512 * 4);
  short* hbuf    = (short*)alloc(4096ull * 512 * 2);
  short* qkv     = (short*)alloc(4096ull * 1536 * 2);
  short* attnout = (short*)alloc(4096ull * 512 * 2);
  short* ffn1    = (short*)alloc(4096ull * 2048 * 2);
  short* xf      = (short*)alloc(4096ull * 512 * 2);

  convert_all_k<<<28312, 256, 0, stream>>>(wq, wk, wv, wo, w1, w2, w_out, bq, bk, bv,
                                           wqkv_bt, wo_bt, w1_bt, w2_bt, wout_bt, bqkv);
  embed_k<<<8192, 256, 0, stream>>>(tokens, tok_emb, x);
  for (int l = 0; l < 4; ++l) {
    layernorm_k<<<4096, 256, 0, stream>>>(x, gamma1 + l * 512, beta1 + l * 512, hbuf);
    gemm64_bt<false, false, true><<<dim3(12, 64), 256, 0, stream>>>(
        hbuf, wqkv_bt + (size_t)l * 786432, bqkv + l * 1536, nullptr, qkv, 4096, 1536, 512);
    attn_k<<<dim3(16, 32), 256, 0, stream>>>(qkv, attnout);
    gemm64_bt<false, true, false><<<dim3(4, 64), 256, 0, stream>>>(
        attnout, wo_bt + (size_t)l * 262144, bo + l * 512, x, x, 4096, 512, 512);
    layernorm_k<<<4096, 256, 0, stream>>>(x, gamma2 + l * 512, beta2 + l * 512, hbuf);
    gemm_bt<true, false, true><<<dim3(16, 32), 256, 0, stream>>>(
        hbuf, w1_bt + (size_t)l * 1048576, b1 + l * 2048, nullptr, ffn1, 4096, 2048, 512);
    gemm64_bt<false, true, false><<<dim3(4, 64), 256, 0, stream>>>(
        ffn1, w2_bt + (size_t)l * 1048576, b2 + l * 512, x, x, 4096, 512, 2048);
  }
  layernorm_k<<<4096, 256, 0, stream>>>(x, gamma_f, beta_f, xf);
  gemm_bt<false, false, false><<<dim3(250, 32), 256, 0, stream>>>(
      xf, wout_bt, b_out, nullptr, d_out, 4096, 32000, 512);
}